// Round 8
// baseline (351.513 us; speedup 1.0000x reference)
//
#include <hip/hip_runtime.h>

#define N_NODES 327680
#define N_EDGES 2621440
#define NGRAPH  8192
#define NB      640          // dst buckets (512 nodes each)
#define BCAPE   4608         // fixed per-bucket capacity (mean 4096, +8 sigma)

typedef unsigned int uint;
typedef unsigned short u16;
typedef __attribute__((ext_vector_type(8))) short s16x8;
typedef __attribute__((ext_vector_type(4))) float f32x4;

__device__ __forceinline__ float bl(uint u){ return __uint_as_float(u << 16); }
__device__ __forceinline__ float bh(uint u){ return __uint_as_float(u & 0xffff0000u); }
__device__ __forceinline__ u16 f2b(float f){
    uint u = __float_as_uint(f);
    u += 0x7fffu + ((u>>16)&1u);          // round-to-nearest-even
    return (u16)(u>>16);
}
__device__ __forceinline__ uint pk(float a, float b){
    return (uint)f2b(a) | ((uint)f2b(b) << 16);
}

// ---------------- prep: weight transposes (bf16) + gcur zero, one launch ----------------

__device__ void tr_tile(const float* __restrict__ in, u16* __restrict__ out,
                        int K, int N, int Kpad, int kb, int nb){
    __shared__ u16 t[64][72];
    for (int i = threadIdx.x; i < 4096; i += 256){
        int k = i >> 6, n = i & 63;
        int gk = kb + k, gn = nb + n;
        float v = (gk < K && gn < N) ? in[(size_t)gk*N + gn] : 0.f;
        t[n][k] = f2b(v);
    }
    __syncthreads();
    for (int i = threadIdx.x; i < 4096; i += 256){
        int n = i >> 6, k = i & 63;
        int gk = kb + k, gn = nb + n;
        if (gn < N && gk < Kpad) out[(size_t)gn*Kpad + gk] = t[n][k];
    }
}

__global__ __launch_bounds__(256) void k_prep(
    const float* __restrict__ W1, const float* __restrict__ W2,
    const float* __restrict__ l1w, const float* __restrict__ l2w,
    u16* __restrict__ w1t, u16* __restrict__ w2t,
    u16* __restrict__ l1wt, u16* __restrict__ l2wt, int* __restrict__ gcur)
{
    int b = blockIdx.x;
    if (b < 120)      tr_tile(l1w, l1wt, 1920, 256, 1920, (b%30)*64, (b/30)*64);
    else if (b < 124) tr_tile(l2w, l2wt, 256,  64,  256,  (b-120)*64, 0);
    else if (b < 126) tr_tile(W1,  w1t,  58,   96,  64,   0, (b-124)*64);
    else if (b < 128) tr_tile(W2,  w2t,  96,   48,  96,   (b-126)*64, 0);
    else {
        for (int i = threadIdx.x; i < NB; i += 256) gcur[i] = 0;
    }
}

// ---------------- partition edges into fixed-cap dst-buckets (packed uint) ----------------

__global__ __launch_bounds__(256) void k_partition(
    const int* __restrict__ src, const int* __restrict__ dst,
    int* __restrict__ gcur, uint* __restrict__ staging)
{
    __shared__ int cnt[NB], base_[NB];
    int tid = threadIdx.x;
    for (int i = tid; i < NB; i += 256) cnt[i] = 0;
    __syncthreads();
    int e0 = blockIdx.x*4096;
    int d[16];
    #pragma unroll
    for (int j = 0; j < 16; ++j){
        d[j] = dst[e0 + j*256 + tid];
        atomicAdd(&cnt[d[j] >> 9], 1);
    }
    __syncthreads();
    for (int i = tid; i < NB; i += 256)
        base_[i] = atomicAdd(&gcur[i], cnt[i]);
    __syncthreads();
    for (int i = tid; i < NB; i += 256) cnt[i] = 0;
    __syncthreads();
    #pragma unroll
    for (int j = 0; j < 16; ++j){
        int e = e0 + j*256 + tid;
        int b = d[j] >> 9;
        int r = atomicAdd(&cnt[b], 1);
        staging[(uint)b*BCAPE + base_[b] + r] = (uint)src[e] | ((uint)(d[j] & 511) << 19);
    }
}

// ---- per-bucket: degree, dinv, row starts, csr place, degree-sorted perm, x prescale ----

__global__ __launch_bounds__(512) void k_bucket(
    const uint* __restrict__ staging, const int* __restrict__ gcur,
    const float* __restrict__ x,
    int* __restrict__ rowst, int* __restrict__ rendg, float* __restrict__ dinvg,
    int* __restrict__ csr, int* __restrict__ perm, uint* __restrict__ xs32)
{
    __shared__ uint sedge[BCAPE];
    __shared__ int deg[512];
    __shared__ int sc[512];
    __shared__ int cur[512];
    __shared__ int dh[64], dbase[64];
    __shared__ float sdinv[512];
    const int b = blockIdx.x;
    const int tid = threadIdx.x;
    const int lo = b*BCAPE;
    int cnt = gcur[b];
    if (cnt > BCAPE) cnt = BCAPE;   // safety (8-sigma margin, never expected)
    deg[tid] = 0;
    if (tid < 64) dh[tid] = 0;
    __syncthreads();
    for (int t = tid; t < cnt; t += 512){
        uint ed = staging[lo + t];
        sedge[t] = ed;
        atomicAdd(&deg[ed >> 19], 1);
    }
    __syncthreads();
    int d = deg[tid];
    sc[tid] = d;
    __syncthreads();
    for (int o = 1; o < 512; o <<= 1){
        int v = (tid >= o) ? sc[tid-o] : 0;
        __syncthreads();
        sc[tid] += v;
        __syncthreads();
    }
    int incl = sc[tid];
    int excl = incl - d;
    int gnode = b*512 + tid;
    float dv = 1.0f / sqrtf((float)(d + 1));
    rowst[gnode] = lo + excl;
    rendg[gnode] = lo + incl;
    dinvg[gnode] = dv;
    sdinv[tid] = dv;
    cur[tid] = lo + excl;
    int bin = min(d, 63);
    atomicAdd(&dh[bin], 1);
    __syncthreads();
    if (tid == 0){
        int a = 0;
        #pragma unroll
        for (int i = 0; i < 64; ++i){ dbase[i] = a; a += dh[i]; dh[i] = 0; }
    }
    __syncthreads();
    int pos = dbase[bin] + atomicAdd(&dh[bin], 1);
    perm[b*512 + pos] = gnode;
    for (int t = tid; t < cnt; t += 512){
        uint ed = sedge[t];
        int p = atomicAdd(&cur[ed >> 19], 1);
        csr[p] = (int)(ed & 0x7FFFFu);
    }
    // prescale this bucket's 512 nodes: xs[node][32] = pk(x*dinv), pad cols>=58
    const size_t n0 = (size_t)b*512;
    for (int i = tid; i < 512*32; i += 512){
        int n = i >> 5, c = i & 31;
        float dvn = sdinv[n];
        float a = 0.f, bb = 0.f;
        if (c < 29){
            float2 v = *(const float2*)&x[(n0 + n)*58 + 2*c];
            a = v.x * dvn; bb = v.y * dvn;
        }
        xs32[(n0 + n)*32 + c] = pk(a, bb);
    }
}

// ---- fused conv1: gather(64 perm'd nodes) -> MFMA W1/relu/W2 -> ts[node] (dense 48) ----

__global__ __launch_bounds__(256) void k_fused1(
    const int* __restrict__ rs, const int* __restrict__ re,
    const int* __restrict__ csr, const float* __restrict__ dinv,
    const int* __restrict__ perm,
    const uint4* __restrict__ feat4,   // xs [N] rows of 128B packed bf16
    const u16* __restrict__ w1t,       // [96][64]
    const float* __restrict__ b1,
    const u16* __restrict__ w2t,       // [48][96]
    u16* __restrict__ ts)              // dense [N][48], prescaled by dinv
{
    __shared__ __align__(16) u16 As[64][72];
    __shared__ __align__(16) u16 Bt1[96][72];
    __shared__ __align__(16) u16 Bt2[48][104];
    __shared__ __align__(16) u16 sh1[64][104];
    __shared__ float sb1[96];
    __shared__ int   snode[64];
    __shared__ float sdv[64];
    const int tid = threadIdx.x;

    // weight / bias LDS fills (independent of gather)
    for (int i = tid; i < 768; i += 256){
        int n = i >> 3, s = i & 7;
        *(uint4*)&Bt1[n][s*8] = *(const uint4*)&w1t[n*64 + s*8];
    }
    for (int i = tid; i < 576; i += 256){
        int n = i / 12, s = i % 12;
        *(uint4*)&Bt2[n][s*8] = *(const uint4*)&w2t[n*96 + s*8];
    }
    if (tid < 96) sb1[tid] = b1[tid];

    // gather: 32 groups x 8 lanes, 2 passes -> 64 rows into As
    {
        const int g = tid >> 3, c4 = tid & 7;
        #pragma unroll
        for (int pass = 0; pass < 2; ++pass){
            int row = pass*32 + g;
            int node = perm[blockIdx.x*64 + row];
            float di = dinv[node];
            uint4 u = feat4[((uint)node << 3) + c4];
            float a0 = bl(u.x), a1 = bh(u.x), a2 = bl(u.y), a3 = bh(u.y);
            float a4 = bl(u.z), a5 = bh(u.z), a6 = bl(u.w), a7 = bh(u.w);
            int e = rs[node];
            const int e1 = re[node];
            while (e < e1){
                const int last = e1 - 1;
                int idx[8];
                #pragma unroll
                for (int k = 0; k < 8; ++k) idx[k] = csr[min(e + k, last)];
                uint4 uu[8];
                #pragma unroll
                for (int k = 0; k < 8; ++k) uu[k] = feat4[((uint)idx[k] << 3) + c4];
                #pragma unroll
                for (int k = 0; k < 8; ++k){
                    if (e + k < e1){
                        a0 += bl(uu[k].x); a1 += bh(uu[k].x);
                        a2 += bl(uu[k].y); a3 += bh(uu[k].y);
                        a4 += bl(uu[k].z); a5 += bh(uu[k].z);
                        a6 += bl(uu[k].w); a7 += bh(uu[k].w);
                    }
                }
                e += 8;
            }
            a0 *= di; a1 *= di; a2 *= di; a3 *= di;
            a4 *= di; a5 *= di; a6 *= di; a7 *= di;
            if (c4 == 0){ snode[row] = node; sdv[row] = di; }
            uint4 w;
            w.x = pk(a0,a1); w.y = pk(a2,a3); w.z = pk(a4,a5); w.w = pk(a6,a7);
            *(uint4*)&As[row][c4*8] = w;
        }
    }
    __syncthreads();

    const int wv = tid >> 6, l = tid & 63;
    const int lr = l & 15, lg = l >> 4;
    const int r0 = wv*16;

    f32x4 acc1[6] = {};
    #pragma unroll
    for (int s = 0; s < 2; ++s){
        s16x8 af = *(const s16x8*)&As[r0+lr][s*32 + lg*8];
        #pragma unroll
        for (int t = 0; t < 6; ++t){
            s16x8 bf = *(const s16x8*)&Bt1[t*16+lr][s*32 + lg*8];
            acc1[t] = __builtin_amdgcn_mfma_f32_16x16x32_bf16(af, bf, acc1[t], 0, 0, 0);
        }
    }
    #pragma unroll
    for (int t = 0; t < 6; ++t){
        int col = t*16 + lr;
        float bias = sb1[col];
        #pragma unroll
        for (int r = 0; r < 4; ++r)
            sh1[r0 + lg*4 + r][col] = f2b(fmaxf(acc1[t][r] + bias, 0.f));
    }
    __syncthreads();

    f32x4 acc2[3] = {};
    #pragma unroll
    for (int s = 0; s < 3; ++s){
        s16x8 af = *(const s16x8*)&sh1[r0+lr][s*32 + lg*8];
        #pragma unroll
        for (int t = 0; t < 3; ++t){
            s16x8 bf = *(const s16x8*)&Bt2[t*16+lr][s*32 + lg*8];
            acc2[t] = __builtin_amdgcn_mfma_f32_16x16x32_bf16(af, bf, acc2[t], 0, 0, 0);
        }
    }
    #pragma unroll
    for (int r = 0; r < 4; ++r){
        int row = r0 + lg*4 + r;
        size_t node = (size_t)snode[row];
        float dv = sdv[row];
        #pragma unroll
        for (int t = 0; t < 3; ++t)
            ts[node*48 + t*16 + lr] = f2b(acc2[t][r] * dv);
    }
}

// ---- conv2 gather: 8 lanes/node x uint3 (12B, dense 48), 8 edges batched ----

__global__ __launch_bounds__(256) void k_gather2(
    const int* __restrict__ rs, const int* __restrict__ re,
    const int* __restrict__ csr, const float* __restrict__ dinv,
    const int* __restrict__ perm,
    const uint* __restrict__ feat,     // ts as uint[N][24] (dense 48 bf16)
    const float* __restrict__ bias,
    uint* __restrict__ out)            // agg2 as uint[N][24]
{
    int slot = (blockIdx.x*256 + threadIdx.x) >> 3;
    int c4 = threadIdx.x & 7;
    int node = perm[slot];
    uint3 u = *(const uint3*)&feat[(size_t)node*24 + c4*3];
    float a0 = bl(u.x), a1 = bh(u.x), a2 = bl(u.y), a3 = bh(u.y);
    float a4 = bl(u.z), a5 = bh(u.z);
    int e = rs[node];
    const int e1 = re[node];
    while (e < e1){
        const int last = e1 - 1;
        int idx[8];
        #pragma unroll
        for (int k = 0; k < 8; ++k) idx[k] = csr[min(e + k, last)];
        uint3 uu[8];
        #pragma unroll
        for (int k = 0; k < 8; ++k) uu[k] = *(const uint3*)&feat[(size_t)idx[k]*24 + c4*3];
        #pragma unroll
        for (int k = 0; k < 8; ++k){
            if (e + k < e1){
                a0 += bl(uu[k].x); a1 += bh(uu[k].x);
                a2 += bl(uu[k].y); a3 += bh(uu[k].y);
                a4 += bl(uu[k].z); a5 += bh(uu[k].z);
            }
        }
        e += 8;
    }
    float di = dinv[node];
    a0 = fmaxf(a0*di + bias[6*c4+0], 0.f);
    a1 = fmaxf(a1*di + bias[6*c4+1], 0.f);
    a2 = fmaxf(a2*di + bias[6*c4+2], 0.f);
    a3 = fmaxf(a3*di + bias[6*c4+3], 0.f);
    a4 = fmaxf(a4*di + bias[6*c4+4], 0.f);
    a5 = fmaxf(a5*di + bias[6*c4+5], 0.f);
    uint3 w;
    w.x = pk(a0,a1); w.y = pk(a2,a3); w.z = pk(a4,a5);
    *(uint3*)&out[(size_t)node*24 + c4*3] = w;
}

// ---------------- fused MLP head: 32 graphs/block, g1 in LDS, l2/l3 fused ----------------

__global__ __launch_bounds__(256) void k_head(
    const u16* __restrict__ A,      // agg2, graph rows [8192][1920] bf16
    const u16* __restrict__ l1wt,   // [256][1920]
    const float* __restrict__ l1b,
    const u16* __restrict__ l2wt,   // [64][256]
    const float* __restrict__ l2b,
    const float* __restrict__ l3w, const float* __restrict__ l3b,
    float* __restrict__ out)
{
    __shared__ __align__(16) u16 As[32][72];
    __shared__ __align__(16) u16 Bt[256][72];
    __shared__ float part[32][2];
    u16 (*sh1)[264] = (u16(*)[264])&Bt[0][0];
    const int tid = threadIdx.x;
    const int g0 = blockIdx.x*32;
    const int w = tid >> 6, l = tid & 63;
    const int lr = l & 15, lg = l >> 4;
    const int r0 = (w & 1)*16;
    const int c0 = (w >> 1)*128;
    f32x4 acc[8] = {};
    for (int k0 = 0; k0 < 1920; k0 += 64){
        __syncthreads();
        {
            int r = tid >> 3, s = tid & 7;
            *(uint4*)&As[r][s*8] = *(const uint4*)&A[(size_t)(g0+r)*1920 + k0 + s*8];
        }
        for (int i = tid; i < 2048; i += 256){
            int n = i >> 3, s = i & 7;
            *(uint4*)&Bt[n][s*8] = *(const uint4*)&l1wt[(size_t)n*1920 + k0 + s*8];
        }
        __syncthreads();
        #pragma unroll
        for (int s = 0; s < 2; ++s){
            s16x8 af = *(const s16x8*)&As[r0+lr][s*32 + lg*8];
            #pragma unroll
            for (int t = 0; t < 8; ++t){
                s16x8 bf = *(const s16x8*)&Bt[c0 + t*16 + lr][s*32 + lg*8];
                acc[t] = __builtin_amdgcn_mfma_f32_16x16x32_bf16(af, bf, acc[t], 0, 0, 0);
            }
        }
    }
    __syncthreads();   // everyone done reading Bt before overlay write
    #pragma unroll
    for (int t = 0; t < 8; ++t){
        int col = c0 + t*16 + lr;
        float bs = l1b[col];
        #pragma unroll
        for (int r = 0; r < 4; ++r)
            sh1[r0 + lg*4 + r][col] = f2b(fmaxf(acc[t][r] + bs, 0.f));
    }
    __syncthreads();
    f32x4 acc2[2] = {};
    #pragma unroll
    for (int s = 0; s < 8; ++s){
        s16x8 af = *(const s16x8*)&sh1[r0+lr][s*32 + lg*8];
        #pragma unroll
        for (int t = 0; t < 2; ++t){
            int col = (w>>1)*32 + t*16 + lr;
            s16x8 bf = *(const s16x8*)&l2wt[(size_t)col*256 + s*32 + lg*8];
            acc2[t] = __builtin_amdgcn_mfma_f32_16x16x32_bf16(af, bf, acc2[t], 0, 0, 0);
        }
    }
    float p[4];
    #pragma unroll
    for (int r = 0; r < 4; ++r){
        p[r] = 0.f;
        #pragma unroll
        for (int t = 0; t < 2; ++t){
            int col = (w>>1)*32 + t*16 + lr;
            p[r] += fmaxf(acc2[t][r] + l2b[col], 0.f) * l3w[col];
        }
    }
    #pragma unroll
    for (int o = 1; o < 16; o <<= 1){
        #pragma unroll
        for (int r = 0; r < 4; ++r) p[r] += __shfl_xor(p[r], o);
    }
    if (lr == 0){
        #pragma unroll
        for (int r = 0; r < 4; ++r)
            part[r0 + lg*4 + r][w>>1] = p[r];
    }
    __syncthreads();
    if (tid < 32)
        out[g0 + tid] = 1.0f / (1.0f + expf(-(part[tid][0] + part[tid][1] + l3b[0])));
}

extern "C" void kernel_launch(void* const* d_in, const int* in_sizes, int n_in,
                              void* d_out, int out_size, void* d_ws, size_t ws_size,
                              hipStream_t stream){
    const float* x   = (const float*)d_in[0];
    const int*   ei  = (const int*)  d_in[1];
    const int*   src = ei;
    const int*   dst = ei + N_EDGES;
    const float* W1  = (const float*)d_in[2];
    const float* b1  = (const float*)d_in[3];
    const float* W2  = (const float*)d_in[4];
    const float* b2  = (const float*)d_in[5];
    const float* l1w = (const float*)d_in[6];
    const float* l1b = (const float*)d_in[7];
    const float* l2w = (const float*)d_in[8];
    const float* l2b = (const float*)d_in[9];
    const float* l3w = (const float*)d_in[10];
    const float* l3b = (const float*)d_in[11];
    float* out = (float*)d_out;

    char* w = (char*)d_ws;
    auto alloc = [&](size_t bytes){ void* p = (void*)w; w += (bytes + 255) & ~(size_t)255; return p; };
    float* dinv    = (float*)alloc((size_t)N_NODES*4);
    int*   rowst   = (int*)  alloc((size_t)N_NODES*4);
    int*   rend    = (int*)  alloc((size_t)N_NODES*4);
    int*   perm    = (int*)  alloc((size_t)N_NODES*4);
    int*   gcur    = (int*)  alloc(NB*4);
    u16*   w1t     = (u16*)  alloc(96*64*2);
    u16*   w2t     = (u16*)  alloc(48*96*2);
    u16*   l1wt    = (u16*)  alloc((size_t)256*1920*2);
    u16*   l2wt    = (u16*)  alloc((size_t)64*256*2);
    int*   csr     = (int*)  alloc((size_t)NB*BCAPE*4);
    uint*  staging = (uint*) alloc((size_t)NB*BCAPE*4);
    uint*  xs32    = (uint*) alloc((size_t)N_NODES*32*4);   // x*dinv, bf16x2 packed, 64 cols
    u16*   ts      = (u16*)  alloc((size_t)N_NODES*48*2);   // conv1 out, dense, prescaled
    u16*   agg2    = (u16*)  alloc((size_t)N_NODES*48*2);   // conv2 out == [8192][1920]

    // prep: weight transposes + gcur zero (one launch)
    k_prep     <<<129, 256, 0, stream>>>(W1, W2, l1w, l2w, w1t, w2t, l1wt, l2wt, gcur);

    // bucketed CSR build (fixed-cap buckets) + fused x prescale
    k_partition<<<640, 256, 0, stream>>>(src, dst, gcur, staging);
    k_bucket   <<<640, 512, 0, stream>>>(staging, gcur, x, rowst, rend, dinv, csr, perm, xs32);

    // conv1: fused gather + W1/relu/W2 (MFMA), dense-48 prescaled output
    k_fused1   <<<5120, 256, 0, stream>>>(rowst, rend, csr, dinv, perm,
                                          (const uint4*)xs32, w1t, b1, w2t, ts);

    // conv2: gather (dense 48) + bias + relu -> agg2
    k_gather2  <<<10240, 256, 0, stream>>>(rowst, rend, csr, dinv, perm,
                                           (const uint*)ts, b2, (uint*)agg2);

    // fused MLP head
    k_head     <<<256, 256, 0, stream>>>(agg2, l1wt, l1b, l2wt, l2b, l3w, l3b, out);
}